// Round 5
// baseline (400.412 us; speedup 1.0000x reference)
//
#include <hip/hip_runtime.h>
#include <hip/hip_cooperative_groups.h>
#include <math.h>

namespace cg = cooperative_groups;

#define BB 4
#define NN 65536
#define G 64
#define G3 (G*G*G)
#define CF 32
#define HF 128
#define WF 128
#define VSc 0.05f
#define R2c 1.5625f   // 1.25^2, exactly representable

// d_ws layout (bytes):
//  [0, B*G3)            : occ bytes (bit0 = inb&nearby, bit1 = inb)  1 MB (memset 0)
//  ANY_OFF = B*G3       : any[B] int (memset 0)
//  PART_OFF = +64       : partials[4096] float4 (fully written)      64 KB
//  FMT_OFF              : fmapT[B][H][W][C] float                    8.4 MB
#define ANY_OFF  (BB*G3)
#define PART_OFF (ANY_OFF + 64)
#define FMT_OFF  (PART_OFF + 4096*16)

typedef __attribute__((ext_vector_type(8))) short short8;
typedef __attribute__((ext_vector_type(4))) float floatx4;

__device__ __forceinline__ ushort f2bf(float x) {
    union { float f; unsigned u; } v; v.f = x;
    unsigned r = v.u + 0x7FFF + ((v.u >> 16) & 1);   // RNE
    return (ushort)(r >> 16);
}

// ================= phase 1: points scatter + fmap transpose (grid-stride) ========
__device__ __forceinline__ void phase_prep(
    int blk0, int NB, int tid,
    const float* __restrict__ pts, const float* __restrict__ pelvis,
    const float* __restrict__ fmap, float* __restrict__ fmapT,
    unsigned* __restrict__ occW, int* __restrict__ any, float* tile)
{
    for (int w = blk0; w < 1024; w += NB) {
        // ---- points chunk w (256 points) ----
        {
            int idx = w * 256 + tid;            // B*N = 262144
            int b = idx >> 16;
            const float* p = pts + (size_t)idx * 3;
            float px = p[0], py = p[1], pz = p[2];
            float ax = pelvis[b * 3 + 0], ay = pelvis[b * 3 + 1], az = pelvis[b * 3 + 2];

            float dx = px - ax, dy = py - ay, dz = pz - az;
            float rxy = dx * dx + dy * dy;
            float d0 = dz * dz;
            float dm = (dz + 0.5f) * (dz + 0.5f);
            float dp = (dz - 0.5f) * (dz - 0.5f);
            bool nearby = (rxy + fminf(d0, fminf(dm, dp))) <= R2c;

            int vx = (int)floorf(px / VSc);
            int vy = (int)floorf(py / VSc);
            int vz = (int)floorf(pz / VSc);
            int v0x = (int)floorf(ax / VSc) - 32;
            int v0y = (int)floorf(ay / VSc) - 32;
            int v0z = (int)floorf(az / VSc) - 32;
            int lx = vx - v0x, ly = vy - v0y, lz = vz - v0z;
            bool inb = ((unsigned)lx < 64u) && ((unsigned)ly < 64u) && ((unsigned)lz < 64u);
            if (inb) {
                int flat = b * G3 + (lx << 12) + (ly << 6) + lz;
                unsigned mask = (nearby ? 3u : 2u) << ((flat & 3) * 8);
                atomicOr(occW + (flat >> 2), mask);
            }
            unsigned long long bal = __ballot(nearby);
            if ((tid & 63) == 0 && bal != 0ULL) atomicOr(&any[b], 1);
        }
        // ---- transpose tile w: fmap [B,C,H,W] -> fmapT [B,H,W,C] ----
        __syncthreads();            // prior iteration's tile reads complete
        {
            int xc = (w & 1) * 64;
            int y  = (w >> 1) & (HF - 1);
            int b  = w >> 8;
#pragma unroll
            for (int i = 0; i < 8; ++i) {
                int e = i * 256 + tid;
                int c = e >> 6, pp = e & 63;
                tile[c * 65 + pp] = fmap[(((size_t)b * CF + c) * HF + y) * WF + xc + pp];
            }
            __syncthreads();
#pragma unroll
            for (int i = 0; i < 8; ++i) {
                int e = i * 256 + tid;
                int pp = e >> 5, c = e & 31;
                fmapT[(((size_t)b * HF + y) * WF + xc + pp) * CF + c] = tile[c * 65 + pp];
            }
        }
    }
}

// ================= phase 2: voxel bilinear + MFMA MLP (grid-stride chunks) =======
__device__ __forceinline__ void phase_voxel(
    int blk0, int NB, int tid,
    const float* __restrict__ fmapT, const float* __restrict__ pelvis,
    const float* __restrict__ Kmat, const float* __restrict__ bbx,
    const float* __restrict__ W1, const float* __restrict__ b1,
    const float* __restrict__ W2, const float* __restrict__ b2,
    const unsigned char* __restrict__ occ, const int* __restrict__ any,
    float4* __restrict__ partials, float* __restrict__ outBig,
    char* ldsBase, float* red)
{
    int wv = tid >> 6, lane = tid & 63;
    int quad = lane >> 4, n16 = lane & 15;
    ushort* A = (ushort*)(ldsBase + wv * 9216);   // 64 rows x 72 ushorts
    float* O  = (float*)(ldsBase + wv * 9216);    // 64 rows x 20 floats

    // ---- weight B-fragments, loaded once (wave-invariant, L1 broadcast) ----
    short8 B1f[2][4];
#pragma unroll
    for (int kt = 0; kt < 2; ++kt)
#pragma unroll
        for (int nt = 0; nt < 4; ++nt) {
            short8 w;
#pragma unroll
            for (int j = 0; j < 8; ++j) {
                int kk = kt * 32 + quad * 8 + j;
                int row = (kk < 32) ? (3 + kk) : (kk - 32);
                w[j] = (kk < 35) ? (short)f2bf(W1[row * 64 + nt * 16 + n16]) : (short)0;
            }
            B1f[kt][nt] = w;
        }
    short8 B2f[2];
#pragma unroll
    for (int kt = 0; kt < 2; ++kt) {
        short8 w;
#pragma unroll
        for (int j = 0; j < 8; ++j) {
            int kk = kt * 32 + quad * 8 + j;
            w[j] = (n16 < 12) ? (short)f2bf(W2[kk * 12 + n16]) : (short)0;
        }
        B2f[kt] = w;
    }
    float b1v[4];
#pragma unroll
    for (int nt = 0; nt < 4; ++nt) b1v[nt] = b1[nt * 16 + n16];
    float b2v = (n16 < 12) ? b2[n16] : 0.0f;

    for (int cid = blk0; cid < 4096; cid += NB) {
        int b = cid >> 10;
        int g = ((cid & 1023) << 8) + (wv << 6) + lane;

        float ax = pelvis[b * 3 + 0], ay = pelvis[b * 3 + 1], az = pelvis[b * 3 + 2];
        float fx = Kmat[b * 9 + 0], fy = Kmat[b * 9 + 4];
        float cxp = Kmat[b * 9 + 2], cyp = Kmat[b * 9 + 5];
        float l = bbx[b * 4 + 0], t = bbx[b * 4 + 1];
        float r = bbx[b * 4 + 2], btm = bbx[b * 4 + 3];
        float inv_w = 1.0f / (r - l), inv_h = 1.0f / (btm - t);

        int v0x = (int)floorf(ax / VSc) - 32;
        int v0y = (int)floorf(ay / VSc) - 32;
        int v0z = (int)floorf(az / VSc) - 32;

        int gx = g >> 12, gy = (g >> 6) & 63, gz = g & 63;
        float cxx = (float)(v0x + gx) * VSc + 0.025f;
        float cyy = (float)(v0y + gy) * VSc + 0.025f;
        float czz = (float)(v0z + gz) * VSc + 0.025f;

        float feat[35];
        feat[32] = ax - cxx;
        feat[33] = ay - cyy;
        feat[34] = az - czz;

        float z = czz;
        float u = cxx / z * fx + cxp;
        float vp = cyy / z * fy + cyp;
        float uu = (u - l) * inv_w * (float)(WF - 1);
        float vv = (vp - t) * inv_h * (float)(HF - 1);
        float x0f = floorf(uu), y0f = floorf(vv);
        float wx = uu - x0f, wy = vv - y0f;
        int x0 = (int)x0f, y0 = (int)y0f;
        int x1 = x0 + 1, y1 = y0 + 1;
        bool mx0 = (unsigned)x0 < (unsigned)WF;
        bool mx1 = (unsigned)x1 < (unsigned)WF;
        bool my0 = (unsigned)y0 < (unsigned)HF;
        bool my1 = (unsigned)y1 < (unsigned)HF;
        int xc0 = min(max(x0, 0), WF - 1), xc1 = min(max(x1, 0), WF - 1);
        int yc0 = min(max(y0, 0), HF - 1), yc1 = min(max(y1, 0), HF - 1);
        float w00 = (1.0f - wx) * (1.0f - wy) * ((mx0 && my0) ? 1.0f : 0.0f);
        float w10 = wx * (1.0f - wy) * ((mx1 && my0) ? 1.0f : 0.0f);
        float w01 = (1.0f - wx) * wy * ((mx0 && my1) ? 1.0f : 0.0f);
        float w11 = wx * wy * ((mx1 && my1) ? 1.0f : 0.0f);

        const float* fb = fmapT + (size_t)b * HF * WF * CF;
        const float* p00 = fb + (yc0 * WF + xc0) * CF;
        const float* p10 = fb + (yc0 * WF + xc1) * CF;
        const float* p01 = fb + (yc1 * WF + xc0) * CF;
        const float* p11 = fb + (yc1 * WF + xc1) * CF;
#pragma unroll
        for (int c = 0; c < CF; c += 4) {
            float4 a00 = *(const float4*)(p00 + c);
            float4 a10 = *(const float4*)(p10 + c);
            float4 a01 = *(const float4*)(p01 + c);
            float4 a11 = *(const float4*)(p11 + c);
            feat[c + 0] = fmaf(a11.x, w11, fmaf(a01.x, w01, fmaf(a10.x, w10, a00.x * w00)));
            feat[c + 1] = fmaf(a11.y, w11, fmaf(a01.y, w01, fmaf(a10.y, w10, a00.y * w00)));
            feat[c + 2] = fmaf(a11.z, w11, fmaf(a01.z, w01, fmaf(a10.z, w10, a00.z * w00)));
            feat[c + 3] = fmaf(a11.w, w11, fmaf(a01.w, w01, fmaf(a10.w, w10, a00.w * w00)));
        }

        __syncthreads();   // prior iteration's O/red reads complete before A overwrite
        // pack feat -> bf16 A-tile (row stride 72 ushorts)
#pragma unroll
        for (int i = 0; i < 8; ++i) {
            short8 pk;
#pragma unroll
            for (int e = 0; e < 8; ++e) {
                int k = i * 8 + e;
                pk[e] = (short)((k < 35) ? f2bf(feat[k]) : 0);
            }
            *(short8*)(A + lane * 72 + i * 8) = pk;
        }

        // layer 1: 32 MFMA
        floatx4 c1[4][4];
#pragma unroll
        for (int mt = 0; mt < 4; ++mt)
#pragma unroll
            for (int nt = 0; nt < 4; ++nt) {
                floatx4 c = {b1v[nt], b1v[nt], b1v[nt], b1v[nt]};
                c1[mt][nt] = c;
            }
#pragma unroll
        for (int mt = 0; mt < 4; ++mt) {
            short8 a0 = *(short8*)(A + (mt * 16 + n16) * 72 + quad * 8);
            short8 a1 = *(short8*)(A + (mt * 16 + n16) * 72 + 32 + quad * 8);
#pragma unroll
            for (int nt = 0; nt < 4; ++nt) {
                c1[mt][nt] = __builtin_amdgcn_mfma_f32_16x16x32_bf16(a0, B1f[0][nt], c1[mt][nt], 0, 0, 0);
                c1[mt][nt] = __builtin_amdgcn_mfma_f32_16x16x32_bf16(a1, B1f[1][nt], c1[mt][nt], 0, 0, 0);
            }
        }

        // relu -> bf16 -> LDS (h becomes next A-tile)
#pragma unroll
        for (int mt = 0; mt < 4; ++mt)
#pragma unroll
            for (int nt = 0; nt < 4; ++nt)
#pragma unroll
                for (int rr = 0; rr < 4; ++rr) {
                    float hv = fmaxf(c1[mt][nt][rr], 0.0f);
                    A[(mt * 16 + quad * 4 + rr) * 72 + nt * 16 + n16] = f2bf(hv);
                }

        // layer 2: 8 MFMA
        floatx4 c2[4];
#pragma unroll
        for (int mt = 0; mt < 4; ++mt) {
            floatx4 c = {b2v, b2v, b2v, b2v};
            c2[mt] = c;
        }
#pragma unroll
        for (int mt = 0; mt < 4; ++mt) {
            short8 a0 = *(short8*)(A + (mt * 16 + n16) * 72 + quad * 8);
            short8 a1 = *(short8*)(A + (mt * 16 + n16) * 72 + 32 + quad * 8);
            c2[mt] = __builtin_amdgcn_mfma_f32_16x16x32_bf16(a0, B2f[0], c2[mt], 0, 0, 0);
            c2[mt] = __builtin_amdgcn_mfma_f32_16x16x32_bf16(a1, B2f[1], c2[mt], 0, 0, 0);
        }

        // C2 -> LDS (stride 20 floats) -> per-lane out[12]
#pragma unroll
        for (int mt = 0; mt < 4; ++mt)
#pragma unroll
            for (int rr = 0; rr < 4; ++rr)
                O[(mt * 16 + quad * 4 + rr) * 20 + n16] = c2[mt][rr];

        float4 o0 = *(float4*)(O + lane * 20 + 0);
        float4 o1 = *(float4*)(O + lane * 20 + 4);
        float4 o2 = *(float4*)(O + lane * 20 + 8);

        float4* dst = (float4*)(outBig + (size_t)(b * G3 + g) * 12);
        dst[0] = o0; dst[1] = o1; dst[2] = o2;

        // softmax accumulation, fixed max M = 1 (s <= 1 always)
        float sig = 1.0f / (1.0f + expf(-o0.x));
        unsigned char oc = occ[(size_t)b * G3 + g];
        bool on = (oc & 1) || ((oc & 2) && any[b] == 0);
        float e = on ? expf(sig - 1.0f) : 0.0f;
        float s0 = e;
        float s1 = e * (cxx + o0.y);
        float s2 = e * (cyy + o0.z);
        float s3 = e * (czz + o0.w);
#pragma unroll
        for (int off = 32; off > 0; off >>= 1) {
            s0 += __shfl_down(s0, off, 64);
            s1 += __shfl_down(s1, off, 64);
            s2 += __shfl_down(s2, off, 64);
            s3 += __shfl_down(s3, off, 64);
        }
        if (lane == 0) {
            red[wv * 4 + 0] = s0; red[wv * 4 + 1] = s1;
            red[wv * 4 + 2] = s2; red[wv * 4 + 3] = s3;
        }
        __syncthreads();
        if (tid == 0) {
            float t0 = red[0] + red[4] + red[8]  + red[12];
            float t1 = red[1] + red[5] + red[9]  + red[13];
            float t2 = red[2] + red[6] + red[10] + red[14];
            float t3 = red[3] + red[7] + red[11] + red[15];
            partials[cid] = make_float4(t0, t1, t2, t3);
        }
    }
}

// ================= phase 3: reduce 1024 partials per batch =======================
__device__ __forceinline__ void phase_reduce(
    int b, int t, const float4* __restrict__ partials,
    const float* __restrict__ pelvis, float* __restrict__ out, float* sh)
{
    float s0 = 0, s1 = 0, s2 = 0, s3 = 0;
#pragma unroll
    for (int i = 0; i < 4; ++i) {
        float4 p = partials[b * 1024 + i * 256 + t];
        s0 += p.x; s1 += p.y; s2 += p.z; s3 += p.w;
    }
    sh[0 * 256 + t] = s0; sh[1 * 256 + t] = s1;
    sh[2 * 256 + t] = s2; sh[3 * 256 + t] = s3;
    __syncthreads();
    for (int st = 128; st > 0; st >>= 1) {
        if (t < st) {
            sh[0 * 256 + t] += sh[0 * 256 + t + st];
            sh[1 * 256 + t] += sh[1 * 256 + t + st];
            sh[2 * 256 + t] += sh[2 * 256 + t + st];
            sh[3 * 256 + t] += sh[3 * 256 + t + st];
        }
        __syncthreads();
    }
    if (t == 0) {
        float den = sh[0];
        float x = sh[256] / den;
        float y = sh[512] / den;
        float zz = sh[768] / den;
        bool bad = isnan(x) || isnan(y) || isnan(zz);
        out[b * 3 + 0] = bad ? pelvis[b * 3 + 0] : x;
        out[b * 3 + 1] = bad ? pelvis[b * 3 + 1] : y;
        out[b * 3 + 2] = bad ? pelvis[b * 3 + 2] : zz;
    }
}

// ================= cooperative fused kernel ======================================
__global__ __launch_bounds__(256, 4) void fused_kernel(
    const float* pts, const float* fmap, const float* pelvis,
    const float* Kmat, const float* bbx,
    const float* W1, const float* b1, const float* W2, const float* b2,
    unsigned char* occ, int* any, float4* partials, float* fmapT, float* out)
{
    __shared__ __align__(16) char lds[4 * 9216];
    __shared__ float red[16];
    cg::grid_group grid = cg::this_grid();
    int NB = gridDim.x, blk = blockIdx.x, tid = threadIdx.x;

    phase_prep(blk, NB, tid, pts, pelvis, fmap, fmapT, (unsigned*)occ, any, (float*)lds);
    grid.sync();
    phase_voxel(blk, NB, tid, fmapT, pelvis, Kmat, bbx, W1, b1, W2, b2,
                occ, any, partials, out + 12, lds, red);
    grid.sync();
    if (blk < BB) phase_reduce(blk, tid, partials, pelvis, out, (float*)lds);
}

// ================= fallback (non-cooperative) path ===============================
__global__ __launch_bounds__(256) void prep_kernel(
    const float* pts, const float* pelvis, const float* fmap, float* fmapT,
    unsigned char* occ, int* any)
{
    __shared__ float tile[CF * 65];
    phase_prep(blockIdx.x, gridDim.x, threadIdx.x, pts, pelvis, fmap, fmapT,
               (unsigned*)occ, any, tile);
}

__global__ __launch_bounds__(256, 2) void voxel_fb_kernel(
    const float* fmapT, const float* pelvis, const float* Kmat, const float* bbx,
    const float* W1, const float* b1, const float* W2, const float* b2,
    const unsigned char* occ, const int* any, float4* partials, float* out)
{
    __shared__ __align__(16) char lds[4 * 9216];
    __shared__ float red[16];
    phase_voxel(blockIdx.x, gridDim.x, threadIdx.x, fmapT, pelvis, Kmat, bbx,
                W1, b1, W2, b2, occ, any, partials, out + 12, lds, red);
}

__global__ __launch_bounds__(256) void reduce_fb_kernel(
    const float4* partials, const float* pelvis, float* out)
{
    __shared__ float sh[4 * 256];
    phase_reduce(blockIdx.x, threadIdx.x, partials, pelvis, out, sh);
}

extern "C" void kernel_launch(void* const* d_in, const int* in_sizes, int n_in,
                              void* d_out, int out_size, void* d_ws, size_t ws_size,
                              hipStream_t stream) {
    const float* points = (const float*)d_in[0];
    const float* fmap   = (const float*)d_in[1];
    const float* pelvis = (const float*)d_in[2];
    const float* Kmat   = (const float*)d_in[3];
    const float* bbx    = (const float*)d_in[4];
    const float* W1     = (const float*)d_in[5];
    const float* b1     = (const float*)d_in[6];
    const float* W2     = (const float*)d_in[7];
    const float* b2     = (const float*)d_in[8];
    float* out = (float*)d_out;

    char* ws = (char*)d_ws;
    unsigned char* occ  = (unsigned char*)ws;
    int* any            = (int*)(ws + ANY_OFF);
    float4* partials    = (float4*)(ws + PART_OFF);
    float* fmapT        = (float*)(ws + FMT_OFF);

    hipMemsetAsync(ws, 0, ANY_OFF + 64, stream);   // occ + any

    // Host-side occupancy query: pure query (no stream op), deterministic per call.
    int maxB = 0;
    hipError_t qe = hipOccupancyMaxActiveBlocksPerMultiprocessor(
        &maxB, (const void*)fused_kernel, 256, 0);

    hipError_t le = hipErrorUnknown;
    if (qe == hipSuccess && maxB > 0) {
        int grid = maxB * 256;          // 256 CUs on MI355X
        if (grid > 1024) grid = 1024;
        void* args[] = {(void*)&points, (void*)&fmap, (void*)&pelvis, (void*)&Kmat,
                        (void*)&bbx, (void*)&W1, (void*)&b1, (void*)&W2, (void*)&b2,
                        (void*)&occ, (void*)&any, (void*)&partials, (void*)&fmapT,
                        (void*)&out};
        le = hipLaunchCooperativeKernel((const void*)fused_kernel, dim3(grid),
                                        dim3(256), args, 0, stream);
    }
    if (le != hipSuccess) {
        // deterministic fallback: same phases as separate dispatches
        prep_kernel<<<1024, 256, 0, stream>>>(points, pelvis, fmap, fmapT, occ, any);
        voxel_fb_kernel<<<1024, 256, 0, stream>>>(fmapT, pelvis, Kmat, bbx,
                                                  W1, b1, W2, b2, occ, any,
                                                  partials, out);
        reduce_fb_kernel<<<BB, 256, 0, stream>>>(partials, pelvis, out);
    }
}

// Round 6
// 325.596 us; speedup vs baseline: 1.2298x; 1.2298x over previous
//
#include <hip/hip_runtime.h>
#include <hip/hip_cooperative_groups.h>
#include <math.h>

namespace cg = cooperative_groups;

#define BB 4
#define NN 65536
#define G 64
#define G3 (G*G*G)
#define CF 32
#define HF 128
#define WF 128
#define VSc 0.05f
#define R2c 1.5625f   // 1.25^2, exactly representable

// d_ws layout (bytes):
//  [0, B*G3)            : occ bytes (bit0 = inb&nearby, bit1 = inb)  1 MB (memset 0)
//  ANY_OFF = B*G3       : any[B] int (memset 0)
//  PART_OFF = +64       : partials[4096] float4 (fully written)      64 KB
//  FMT_OFF              : fmapT[B][H][W][C] float                    8.4 MB
#define ANY_OFF  (BB*G3)
#define PART_OFF (ANY_OFF + 64)
#define FMT_OFF  (PART_OFF + 4096*16)

typedef __attribute__((ext_vector_type(8))) short short8;
typedef __attribute__((ext_vector_type(4))) float floatx4;

__device__ __forceinline__ ushort f2bf(float x) {
    union { float f; unsigned u; } v; v.f = x;
    unsigned r = v.u + 0x7FFF + ((v.u >> 16) & 1);   // RNE
    return (ushort)(r >> 16);
}

// ================= phase 1: points scatter + fmap transpose (grid-stride) ========
__device__ __forceinline__ void phase_prep(
    int blk0, int NB, int tid,
    const float* __restrict__ pts, const float* __restrict__ pelvis,
    const float* __restrict__ fmap, float* __restrict__ fmapT,
    unsigned* __restrict__ occW, int* __restrict__ any, float* tile)
{
    for (int w = blk0; w < 1024; w += NB) {
        // ---- points chunk w (256 points) ----
        {
            int idx = w * 256 + tid;            // B*N = 262144
            int b = idx >> 16;
            const float* p = pts + (size_t)idx * 3;
            float px = p[0], py = p[1], pz = p[2];
            float ax = pelvis[b * 3 + 0], ay = pelvis[b * 3 + 1], az = pelvis[b * 3 + 2];

            float dx = px - ax, dy = py - ay, dz = pz - az;
            float rxy = dx * dx + dy * dy;
            float d0 = dz * dz;
            float dm = (dz + 0.5f) * (dz + 0.5f);
            float dp = (dz - 0.5f) * (dz - 0.5f);
            bool nearby = (rxy + fminf(d0, fminf(dm, dp))) <= R2c;

            int vx = (int)floorf(px / VSc);
            int vy = (int)floorf(py / VSc);
            int vz = (int)floorf(pz / VSc);
            int v0x = (int)floorf(ax / VSc) - 32;
            int v0y = (int)floorf(ay / VSc) - 32;
            int v0z = (int)floorf(az / VSc) - 32;
            int lx = vx - v0x, ly = vy - v0y, lz = vz - v0z;
            bool inb = ((unsigned)lx < 64u) && ((unsigned)ly < 64u) && ((unsigned)lz < 64u);
            if (inb) {
                int flat = b * G3 + (lx << 12) + (ly << 6) + lz;
                unsigned mask = (nearby ? 3u : 2u) << ((flat & 3) * 8);
                atomicOr(occW + (flat >> 2), mask);
            }
            unsigned long long bal = __ballot(nearby);
            if ((tid & 63) == 0 && bal != 0ULL) atomicOr(&any[b], 1);
        }
        // ---- transpose tile w: fmap [B,C,H,W] -> fmapT [B,H,W,C] ----
        __syncthreads();            // prior iteration's tile reads complete
        {
            int xc = (w & 1) * 64;
            int y  = (w >> 1) & (HF - 1);
            int b  = w >> 8;
#pragma unroll
            for (int i = 0; i < 8; ++i) {
                int e = i * 256 + tid;
                int c = e >> 6, pp = e & 63;
                tile[c * 65 + pp] = fmap[(((size_t)b * CF + c) * HF + y) * WF + xc + pp];
            }
            __syncthreads();
#pragma unroll
            for (int i = 0; i < 8; ++i) {
                int e = i * 256 + tid;
                int pp = e >> 5, c = e & 31;
                fmapT[(((size_t)b * HF + y) * WF + xc + pp) * CF + c] = tile[c * 65 + pp];
            }
        }
    }
}

// ================= phase 2: voxel bilinear + MFMA MLP (grid-stride chunks) =======
__device__ __forceinline__ void phase_voxel(
    int blk0, int NB, int tid,
    const float* __restrict__ fmapT, const float* __restrict__ pelvis,
    const float* __restrict__ Kmat, const float* __restrict__ bbx,
    const float* __restrict__ W1, const float* __restrict__ b1,
    const float* __restrict__ W2, const float* __restrict__ b2,
    const unsigned char* __restrict__ occ, const int* __restrict__ any,
    float4* __restrict__ partials, float* __restrict__ outBig,
    char* ldsBase, float* red)
{
    int wv = tid >> 6, lane = tid & 63;
    int quad = lane >> 4, n16 = lane & 15;
    ushort* A = (ushort*)(ldsBase + wv * 9216);   // 64 rows x 72 ushorts
    float* O  = (float*)(ldsBase + wv * 9216);    // 64 rows x 20 floats

    // ---- weight B-fragments, loaded once (wave-invariant, L1 broadcast) ----
    short8 B1f[2][4];
#pragma unroll
    for (int kt = 0; kt < 2; ++kt)
#pragma unroll
        for (int nt = 0; nt < 4; ++nt) {
            short8 w;
#pragma unroll
            for (int j = 0; j < 8; ++j) {
                int kk = kt * 32 + quad * 8 + j;
                int row = (kk < 32) ? (3 + kk) : (kk - 32);
                w[j] = (kk < 35) ? (short)f2bf(W1[row * 64 + nt * 16 + n16]) : (short)0;
            }
            B1f[kt][nt] = w;
        }
    short8 B2f[2];
#pragma unroll
    for (int kt = 0; kt < 2; ++kt) {
        short8 w;
#pragma unroll
        for (int j = 0; j < 8; ++j) {
            int kk = kt * 32 + quad * 8 + j;
            w[j] = (n16 < 12) ? (short)f2bf(W2[kk * 12 + n16]) : (short)0;
        }
        B2f[kt] = w;
    }
    float b1v[4];
#pragma unroll
    for (int nt = 0; nt < 4; ++nt) b1v[nt] = b1[nt * 16 + n16];
    float b2v = (n16 < 12) ? b2[n16] : 0.0f;

    for (int cid = blk0; cid < 4096; cid += NB) {
        int b = cid >> 10;
        int g = ((cid & 1023) << 8) + (wv << 6) + lane;

        float ax = pelvis[b * 3 + 0], ay = pelvis[b * 3 + 1], az = pelvis[b * 3 + 2];
        float fx = Kmat[b * 9 + 0], fy = Kmat[b * 9 + 4];
        float cxp = Kmat[b * 9 + 2], cyp = Kmat[b * 9 + 5];
        float l = bbx[b * 4 + 0], t = bbx[b * 4 + 1];
        float r = bbx[b * 4 + 2], btm = bbx[b * 4 + 3];
        float inv_w = 1.0f / (r - l), inv_h = 1.0f / (btm - t);

        int v0x = (int)floorf(ax / VSc) - 32;
        int v0y = (int)floorf(ay / VSc) - 32;
        int v0z = (int)floorf(az / VSc) - 32;

        int gx = g >> 12, gy = (g >> 6) & 63, gz = g & 63;
        float cxx = (float)(v0x + gx) * VSc + 0.025f;
        float cyy = (float)(v0y + gy) * VSc + 0.025f;
        float czz = (float)(v0z + gz) * VSc + 0.025f;

        float feat[35];
        feat[32] = ax - cxx;
        feat[33] = ay - cyy;
        feat[34] = az - czz;

        float z = czz;
        float u = cxx / z * fx + cxp;
        float vp = cyy / z * fy + cyp;
        float uu = (u - l) * inv_w * (float)(WF - 1);
        float vv = (vp - t) * inv_h * (float)(HF - 1);
        float x0f = floorf(uu), y0f = floorf(vv);
        float wx = uu - x0f, wy = vv - y0f;
        int x0 = (int)x0f, y0 = (int)y0f;
        int x1 = x0 + 1, y1 = y0 + 1;
        bool mx0 = (unsigned)x0 < (unsigned)WF;
        bool mx1 = (unsigned)x1 < (unsigned)WF;
        bool my0 = (unsigned)y0 < (unsigned)HF;
        bool my1 = (unsigned)y1 < (unsigned)HF;
        int xc0 = min(max(x0, 0), WF - 1), xc1 = min(max(x1, 0), WF - 1);
        int yc0 = min(max(y0, 0), HF - 1), yc1 = min(max(y1, 0), HF - 1);
        float w00 = (1.0f - wx) * (1.0f - wy) * ((mx0 && my0) ? 1.0f : 0.0f);
        float w10 = wx * (1.0f - wy) * ((mx1 && my0) ? 1.0f : 0.0f);
        float w01 = (1.0f - wx) * wy * ((mx0 && my1) ? 1.0f : 0.0f);
        float w11 = wx * wy * ((mx1 && my1) ? 1.0f : 0.0f);

        const float* fb = fmapT + (size_t)b * HF * WF * CF;
        const float* p00 = fb + (yc0 * WF + xc0) * CF;
        const float* p10 = fb + (yc0 * WF + xc1) * CF;
        const float* p01 = fb + (yc1 * WF + xc0) * CF;
        const float* p11 = fb + (yc1 * WF + xc1) * CF;
#pragma unroll
        for (int c = 0; c < CF; c += 4) {
            float4 a00 = *(const float4*)(p00 + c);
            float4 a10 = *(const float4*)(p10 + c);
            float4 a01 = *(const float4*)(p01 + c);
            float4 a11 = *(const float4*)(p11 + c);
            feat[c + 0] = fmaf(a11.x, w11, fmaf(a01.x, w01, fmaf(a10.x, w10, a00.x * w00)));
            feat[c + 1] = fmaf(a11.y, w11, fmaf(a01.y, w01, fmaf(a10.y, w10, a00.y * w00)));
            feat[c + 2] = fmaf(a11.z, w11, fmaf(a01.z, w01, fmaf(a10.z, w10, a00.z * w00)));
            feat[c + 3] = fmaf(a11.w, w11, fmaf(a01.w, w01, fmaf(a10.w, w10, a00.w * w00)));
        }

        __syncthreads();   // prior iteration's O/red reads complete before A overwrite
        // pack feat -> bf16 A-tile (row stride 72 ushorts)
#pragma unroll
        for (int i = 0; i < 8; ++i) {
            short8 pk;
#pragma unroll
            for (int e = 0; e < 8; ++e) {
                int k = i * 8 + e;
                pk[e] = (short)((k < 35) ? f2bf(feat[k]) : 0);
            }
            *(short8*)(A + lane * 72 + i * 8) = pk;
        }

        // layer 1: 32 MFMA
        floatx4 c1[4][4];
#pragma unroll
        for (int mt = 0; mt < 4; ++mt)
#pragma unroll
            for (int nt = 0; nt < 4; ++nt) {
                floatx4 c = {b1v[nt], b1v[nt], b1v[nt], b1v[nt]};
                c1[mt][nt] = c;
            }
#pragma unroll
        for (int mt = 0; mt < 4; ++mt) {
            short8 a0 = *(short8*)(A + (mt * 16 + n16) * 72 + quad * 8);
            short8 a1 = *(short8*)(A + (mt * 16 + n16) * 72 + 32 + quad * 8);
#pragma unroll
            for (int nt = 0; nt < 4; ++nt) {
                c1[mt][nt] = __builtin_amdgcn_mfma_f32_16x16x32_bf16(a0, B1f[0][nt], c1[mt][nt], 0, 0, 0);
                c1[mt][nt] = __builtin_amdgcn_mfma_f32_16x16x32_bf16(a1, B1f[1][nt], c1[mt][nt], 0, 0, 0);
            }
        }

        // relu -> bf16 -> LDS (h becomes next A-tile)
#pragma unroll
        for (int mt = 0; mt < 4; ++mt)
#pragma unroll
            for (int nt = 0; nt < 4; ++nt)
#pragma unroll
                for (int rr = 0; rr < 4; ++rr) {
                    float hv = fmaxf(c1[mt][nt][rr], 0.0f);
                    A[(mt * 16 + quad * 4 + rr) * 72 + nt * 16 + n16] = f2bf(hv);
                }

        // layer 2: 8 MFMA
        floatx4 c2[4];
#pragma unroll
        for (int mt = 0; mt < 4; ++mt) {
            floatx4 c = {b2v, b2v, b2v, b2v};
            c2[mt] = c;
        }
#pragma unroll
        for (int mt = 0; mt < 4; ++mt) {
            short8 a0 = *(short8*)(A + (mt * 16 + n16) * 72 + quad * 8);
            short8 a1 = *(short8*)(A + (mt * 16 + n16) * 72 + 32 + quad * 8);
            c2[mt] = __builtin_amdgcn_mfma_f32_16x16x32_bf16(a0, B2f[0], c2[mt], 0, 0, 0);
            c2[mt] = __builtin_amdgcn_mfma_f32_16x16x32_bf16(a1, B2f[1], c2[mt], 0, 0, 0);
        }

        // C2 -> LDS (stride 20 floats) -> per-lane out[12]
#pragma unroll
        for (int mt = 0; mt < 4; ++mt)
#pragma unroll
            for (int rr = 0; rr < 4; ++rr)
                O[(mt * 16 + quad * 4 + rr) * 20 + n16] = c2[mt][rr];

        float4 o0 = *(float4*)(O + lane * 20 + 0);
        float4 o1 = *(float4*)(O + lane * 20 + 4);
        float4 o2 = *(float4*)(O + lane * 20 + 8);

        float4* dst = (float4*)(outBig + (size_t)(b * G3 + g) * 12);
        dst[0] = o0; dst[1] = o1; dst[2] = o2;

        // softmax accumulation, fixed max M = 1 (s <= 1 always)
        float sig = 1.0f / (1.0f + expf(-o0.x));
        unsigned char oc = occ[(size_t)b * G3 + g];
        bool on = (oc & 1) || ((oc & 2) && any[b] == 0);
        float e = on ? expf(sig - 1.0f) : 0.0f;
        float s0 = e;
        float s1 = e * (cxx + o0.y);
        float s2 = e * (cyy + o0.z);
        float s3 = e * (czz + o0.w);
#pragma unroll
        for (int off = 32; off > 0; off >>= 1) {
            s0 += __shfl_down(s0, off, 64);
            s1 += __shfl_down(s1, off, 64);
            s2 += __shfl_down(s2, off, 64);
            s3 += __shfl_down(s3, off, 64);
        }
        if (lane == 0) {
            red[wv * 4 + 0] = s0; red[wv * 4 + 1] = s1;
            red[wv * 4 + 2] = s2; red[wv * 4 + 3] = s3;
        }
        __syncthreads();
        if (tid == 0) {
            float t0 = red[0] + red[4] + red[8]  + red[12];
            float t1 = red[1] + red[5] + red[9]  + red[13];
            float t2 = red[2] + red[6] + red[10] + red[14];
            float t3 = red[3] + red[7] + red[11] + red[15];
            partials[cid] = make_float4(t0, t1, t2, t3);
        }
    }
}

// ================= phase 3: reduce 1024 partials per batch =======================
__device__ __forceinline__ void phase_reduce(
    int b, int t, const float4* __restrict__ partials,
    const float* __restrict__ pelvis, float* __restrict__ out, float* sh)
{
    float s0 = 0, s1 = 0, s2 = 0, s3 = 0;
#pragma unroll
    for (int i = 0; i < 4; ++i) {
        float4 p = partials[b * 1024 + i * 256 + t];
        s0 += p.x; s1 += p.y; s2 += p.z; s3 += p.w;
    }
    sh[0 * 256 + t] = s0; sh[1 * 256 + t] = s1;
    sh[2 * 256 + t] = s2; sh[3 * 256 + t] = s3;
    __syncthreads();
    for (int st = 128; st > 0; st >>= 1) {
        if (t < st) {
            sh[0 * 256 + t] += sh[0 * 256 + t + st];
            sh[1 * 256 + t] += sh[1 * 256 + t + st];
            sh[2 * 256 + t] += sh[2 * 256 + t + st];
            sh[3 * 256 + t] += sh[3 * 256 + t + st];
        }
        __syncthreads();
    }
    if (t == 0) {
        float den = sh[0];
        float x = sh[256] / den;
        float y = sh[512] / den;
        float zz = sh[768] / den;
        bool bad = isnan(x) || isnan(y) || isnan(zz);
        out[b * 3 + 0] = bad ? pelvis[b * 3 + 0] : x;
        out[b * 3 + 1] = bad ? pelvis[b * 3 + 1] : y;
        out[b * 3 + 2] = bad ? pelvis[b * 3 + 2] : zz;
    }
}

// ================= cooperative fused kernel ======================================
// (256,2): register budget 256/lane. gfx950 has a UNIFIED VGPR/AGPR file — the 64
// MFMA accumulators count against the same budget, so (256,4)'s 128-reg cap forced
// weight/feat spills to scratch (+270 MB HBM traffic, R5). LDS (37 KB) caps
// co-residency at 4 blocks/CU regardless; the host occupancy query sizes the grid.
__global__ __launch_bounds__(256, 2) void fused_kernel(
    const float* pts, const float* fmap, const float* pelvis,
    const float* Kmat, const float* bbx,
    const float* W1, const float* b1, const float* W2, const float* b2,
    unsigned char* occ, int* any, float4* partials, float* fmapT, float* out)
{
    __shared__ __align__(16) char lds[4 * 9216];
    __shared__ float red[16];
    cg::grid_group grid = cg::this_grid();
    int NB = gridDim.x, blk = blockIdx.x, tid = threadIdx.x;

    phase_prep(blk, NB, tid, pts, pelvis, fmap, fmapT, (unsigned*)occ, any, (float*)lds);
    grid.sync();
    phase_voxel(blk, NB, tid, fmapT, pelvis, Kmat, bbx, W1, b1, W2, b2,
                occ, any, partials, out + 12, lds, red);
    grid.sync();
    if (blk < BB) phase_reduce(blk, tid, partials, pelvis, out, (float*)lds);
}

// ================= fallback (non-cooperative) path ===============================
__global__ __launch_bounds__(256) void prep_kernel(
    const float* pts, const float* pelvis, const float* fmap, float* fmapT,
    unsigned char* occ, int* any)
{
    __shared__ float tile[CF * 65];
    phase_prep(blockIdx.x, gridDim.x, threadIdx.x, pts, pelvis, fmap, fmapT,
               (unsigned*)occ, any, tile);
}

__global__ __launch_bounds__(256, 2) void voxel_fb_kernel(
    const float* fmapT, const float* pelvis, const float* Kmat, const float* bbx,
    const float* W1, const float* b1, const float* W2, const float* b2,
    const unsigned char* occ, const int* any, float4* partials, float* out)
{
    __shared__ __align__(16) char lds[4 * 9216];
    __shared__ float red[16];
    phase_voxel(blockIdx.x, gridDim.x, threadIdx.x, fmapT, pelvis, Kmat, bbx,
                W1, b1, W2, b2, occ, any, partials, out + 12, lds, red);
}

__global__ __launch_bounds__(256) void reduce_fb_kernel(
    const float4* partials, const float* pelvis, float* out)
{
    __shared__ float sh[4 * 256];
    phase_reduce(blockIdx.x, threadIdx.x, partials, pelvis, out, sh);
}

extern "C" void kernel_launch(void* const* d_in, const int* in_sizes, int n_in,
                              void* d_out, int out_size, void* d_ws, size_t ws_size,
                              hipStream_t stream) {
    const float* points = (const float*)d_in[0];
    const float* fmap   = (const float*)d_in[1];
    const float* pelvis = (const float*)d_in[2];
    const float* Kmat   = (const float*)d_in[3];
    const float* bbx    = (const float*)d_in[4];
    const float* W1     = (const float*)d_in[5];
    const float* b1     = (const float*)d_in[6];
    const float* W2     = (const float*)d_in[7];
    const float* b2     = (const float*)d_in[8];
    float* out = (float*)d_out;

    char* ws = (char*)d_ws;
    unsigned char* occ  = (unsigned char*)ws;
    int* any            = (int*)(ws + ANY_OFF);
    float4* partials    = (float4*)(ws + PART_OFF);
    float* fmapT        = (float*)(ws + FMT_OFF);

    hipMemsetAsync(ws, 0, ANY_OFF + 64, stream);   // occ + any

    // Host-side occupancy query: pure query (no stream op), deterministic per call.
    int maxB = 0;
    hipError_t qe = hipOccupancyMaxActiveBlocksPerMultiprocessor(
        &maxB, (const void*)fused_kernel, 256, 0);

    hipError_t le = hipErrorUnknown;
    if (qe == hipSuccess && maxB > 0) {
        int grid = maxB * 256;          // 256 CUs on MI355X
        if (grid > 1024) grid = 1024;
        void* args[] = {(void*)&points, (void*)&fmap, (void*)&pelvis, (void*)&Kmat,
                        (void*)&bbx, (void*)&W1, (void*)&b1, (void*)&W2, (void*)&b2,
                        (void*)&occ, (void*)&any, (void*)&partials, (void*)&fmapT,
                        (void*)&out};
        le = hipLaunchCooperativeKernel((const void*)fused_kernel, dim3(grid),
                                        dim3(256), args, 0, stream);
    }
    if (le != hipSuccess) {
        // deterministic fallback: same phases as separate dispatches
        prep_kernel<<<1024, 256, 0, stream>>>(points, pelvis, fmap, fmapT, occ, any);
        voxel_fb_kernel<<<1024, 256, 0, stream>>>(fmapT, pelvis, Kmat, bbx,
                                                  W1, b1, W2, b2, occ, any,
                                                  partials, out);
        reduce_fb_kernel<<<BB, 256, 0, stream>>>(partials, pelvis, out);
    }
}